// Round 11
// baseline (111.425 us; speedup 1.0000x reference)
//
#include <hip/hip_runtime.h>

// ---------- types ----------
typedef _Float16 v8h __attribute__((ext_vector_type(8)));
typedef float    v4f __attribute__((ext_vector_type(4)));

// ---------- helpers ----------
__device__ __forceinline__ void gl_lds16(const void* g, void* l) {
  __builtin_amdgcn_global_load_lds(
      (__attribute__((address_space(1))) void*)(void*)g,
      (__attribute__((address_space(3))) void*)l, 16, 0, 0);
}
__device__ __forceinline__ v8h cvt8(const float4 a, const float4 b) {
  v8h o;
  o[0] = (_Float16)a.x; o[1] = (_Float16)a.y; o[2] = (_Float16)a.z; o[3] = (_Float16)a.w;
  o[4] = (_Float16)b.x; o[5] = (_Float16)b.y; o[6] = (_Float16)b.z; o[7] = (_Float16)b.w;
  return o;
}

// ---------- conversion: both weights fp32 -> fp16 in one launch ----------
__global__ void conv_w(const float4* __restrict__ wp, const float4* __restrict__ wc,
                       v8h* __restrict__ op, v8h* __restrict__ oc) {
  const int n = 73728;  // 768*768/8
  int i = blockIdx.x * blockDim.x + threadIdx.x;
  const float4* src = (i < n) ? wp : wc;
  v8h* dst = (i < n) ? op : oc;
  const int j = (i < n) ? i : i - n;
  dst[j] = cvt8(src[2 * j], src[2 * j + 1]);
}

// ============================================================================
// GEMM1 (round-9 proven structure): BM=BN=64, BK=128, 6 K-iters, 4 waves each
// 32x32 via 2x2 of 16x16x32_f16 MFMA over 4 K-chunks/iter. LDS 64x128 fp16
// XOR-swizzled (elem (row,cg) at phys cg ^ (row&15); staging permutes the
// GLOBAL address, keeping gl_lds's wave-uniform LDS pattern). Grid 64x12=768
// blocks (3/CU), XCD swizzle: blockIdx%8 -> contiguous 8-M-tile band per XCD.
// ============================================================================

// ---------- GEMM1 + quantum head, fused ----------
__global__ __launch_bounds__(256) void gemm1_qh(
    const float* __restrict__ X,          // [4096][768] fp32
    const _Float16* __restrict__ B,       // [768][768] fp16 (W_proj)
    const float* __restrict__ bp,         // [768]
    const float* __restrict__ theta,      // [8]
    _Float16* __restrict__ EZ) {          // [4096][768] fp16
  const int t = threadIdx.x;
  const int b = blockIdx.x;
  const int xcd = b & 7, slot = b >> 3;
  const int bm = xcd * 8 + slot / 12;
  const int bn = slot % 12;

  const int wave = t >> 6, lane = t & 63;
  const int quad = lane >> 4, l16 = lane & 15;
  const int wm = (wave >> 1) * 32, wn = (wave & 1) * 32;

  __shared__ __align__(16) unsigned char smem[32768];
  _Float16* As = (_Float16*)smem;            // 64 x 128 (swizzled)
  _Float16* Bs = (_Float16*)(smem + 16384);  // 64 x 128 (swizzled)
  float* Cs = (float*)smem;                  // epilogue reuse: 64 x 68 fp32

  const float4 th0 = *(const float4*)theta;
  const float4 th1 = *(const float4*)(theta + 4);

  const int tr = t >> 4;          // 0..15 (row-in-group)
  const int tc = t & 15;          // col-group
  const int cgl = tc ^ tr;        // swizzled logical col-group for staging

  const float*    Xg = X + (size_t)(bm * 64 + tr) * 768 + cgl * 8;
  const _Float16* Bg = B + (size_t)(bn * 64 + tr) * 768 + cgl * 8;

  v4f acc[2][2];
#pragma unroll
  for (int i = 0; i < 2; i++)
#pragma unroll
    for (int j = 0; j < 2; j++) acc[i][j] = (v4f){0.f, 0.f, 0.f, 0.f};

  for (int kt = 0; kt < 768; kt += 128) {
    // stage B (async direct-to-LDS), then A (fp32->fp16 via regs) overlapping
#pragma unroll
    for (int c = 0; c < 4; c++)
      gl_lds16(Bg + (size_t)c * 16 * 768 + kt, &Bs[c * 2048 + t * 8]);
#pragma unroll
    for (int c = 0; c < 4; c++) {
      const float* p = Xg + (size_t)c * 16 * 768 + kt;
      const float4 a0 = *(const float4*)p;
      const float4 a1 = *(const float4*)(p + 4);
      *(v8h*)&As[c * 2048 + t * 8] = cvt8(a0, a1);
    }
    __syncthreads();
#pragma unroll
    for (int q = 0; q < 4; q++) {
      v8h af[2], bf[2];
#pragma unroll
      for (int i = 0; i < 2; i++)
        af[i] = *(const v8h*)&As[(wm + i * 16 + l16) * 128 + (((q * 4 + quad) ^ l16) * 8)];
#pragma unroll
      for (int j = 0; j < 2; j++)
        bf[j] = *(const v8h*)&Bs[(wn + j * 16 + l16) * 128 + (((q * 4 + quad) ^ l16) * 8)];
#pragma unroll
      for (int i = 0; i < 2; i++)
#pragma unroll
        for (int j = 0; j < 2; j++)
          acc[i][j] = __builtin_amdgcn_mfma_f32_16x16x32_f16(af[i], bf[j], acc[i][j], 0, 0, 0);
    }
    __syncthreads();
  }

  // ---- epilogue: acc -> LDS (stride 68), then quantum head per row-head ----
  const int r0 = wm + quad * 4;
  const int c0 = wn + l16;
#pragma unroll
  for (int j = 0; j < 2; j++)
#pragma unroll
    for (int i = 0; i < 2; i++)
#pragma unroll
      for (int r = 0; r < 4; r++)
        Cs[(r0 + i * 16 + r) * 68 + c0 + j * 16] = acc[i][j][r];
  __syncthreads();

#pragma unroll
  for (int s = 0; s < 2; s++) {
    const int idx = t + s * 256;          // 0..511 = 64 rows x 8 heads
    const int row = idx >> 3, h = idx & 7;
    const int gcol = bn * 64 + h * 8;
    const float* cr = &Cs[row * 68 + h * 8];
    const float4 q0 = *(const float4*)cr;
    const float4 q1 = *(const float4*)(cr + 4);
    const float4 b0 = *(const float4*)(bp + gcol);
    const float4 b1 = *(const float4*)(bp + gcol + 4);
    float c[8];
    c[0] = cosf(q0.x + b0.x + th0.x);
    c[1] = cosf(q0.y + b0.y + th0.y);
    c[2] = cosf(q0.z + b0.z + th0.z);
    c[3] = cosf(q0.w + b0.w + th0.w);
    c[4] = cosf(q1.x + b1.x + th1.x);
    c[5] = cosf(q1.y + b1.y + th1.y);
    c[6] = cosf(q1.z + b1.z + th1.z);
    c[7] = cosf(q1.w + b1.w + th1.w);
    float e[8];
    e[0] = c[1] * c[2] * c[3] * c[4] * c[5] * c[6] * c[7];
    float pr = c[0];
#pragma unroll
    for (int w = 1; w < 8; w++) { pr *= c[w]; e[w] = pr; }
    v8h ov;
#pragma unroll
    for (int w = 0; w < 8; w++) ov[w] = (_Float16)e[w];
    *(v8h*)(EZ + (size_t)(bm * 64 + row) * 768 + gcol) = ov;
  }
}

// ---------- GEMM2: out = EZ @ Wc^T + bc ----------
// A-fragments load DIRECTLY from global (per-lane 16B contiguous; EZ band is
// L2-resident on the producing XCD thanks to the shared swizzle) -> A is off
// the barrier/LDS path entirely. Only B staged via gl_lds (16 KB, swizzled).
__global__ __launch_bounds__(256) void gemm2(
    const _Float16* __restrict__ A,       // [4096][768] fp16 (EZ)
    const _Float16* __restrict__ B,       // [768][768] fp16 (W_comb)
    float* __restrict__ C,                // [4096][768] fp32
    const float* __restrict__ bias) {
  const int t = threadIdx.x;
  const int b = blockIdx.x;
  const int xcd = b & 7, slot = b >> 3;
  const int bm = xcd * 8 + slot / 12;
  const int bn = slot % 12;

  const int wave = t >> 6, lane = t & 63;
  const int quad = lane >> 4, l16 = lane & 15;
  const int wm = (wave >> 1) * 32, wn = (wave & 1) * 32;

  __shared__ __align__(16) _Float16 Bs[64 * 128];

  const int tr = t >> 4;
  const int tc = t & 15;
  const int cgl = tc ^ tr;
  const _Float16* Bg = B + (size_t)(bn * 64 + tr) * 768 + cgl * 8;

  // global A-fragment bases: row = bm*64 + wm + ii*16 + l16, col = kt + q*32 + quad*8
  const _Float16* Ar0 = A + (size_t)(bm * 64 + wm + l16) * 768 + quad * 8;
  const _Float16* Ar1 = Ar0 + (size_t)16 * 768;

  v4f acc[2][2];
#pragma unroll
  for (int i = 0; i < 2; i++)
#pragma unroll
    for (int j = 0; j < 2; j++) acc[i][j] = (v4f){0.f, 0.f, 0.f, 0.f};

  for (int kt = 0; kt < 768; kt += 128) {
#pragma unroll
    for (int c = 0; c < 4; c++)
      gl_lds16(Bg + (size_t)c * 16 * 768 + kt, &Bs[c * 2048 + t * 8]);
    __syncthreads();
#pragma unroll
    for (int q = 0; q < 4; q++) {
      v8h af[2], bf[2];
      af[0] = *(const v8h*)(Ar0 + kt + q * 32);
      af[1] = *(const v8h*)(Ar1 + kt + q * 32);
#pragma unroll
      for (int j = 0; j < 2; j++)
        bf[j] = *(const v8h*)&Bs[(wn + j * 16 + l16) * 128 + (((q * 4 + quad) ^ l16) * 8)];
#pragma unroll
      for (int ii = 0; ii < 2; ii++)
#pragma unroll
        for (int j = 0; j < 2; j++)
          acc[ii][j] = __builtin_amdgcn_mfma_f32_16x16x32_f16(af[ii], bf[j], acc[ii][j], 0, 0, 0);
    }
    __syncthreads();
  }

  const int row0 = bm * 64 + wm + quad * 4;
  const int col0 = bn * 64 + wn + l16;
#pragma unroll
  for (int j = 0; j < 2; j++) {
    const int col = col0 + j * 16;
    const float bv = bias[col];
#pragma unroll
    for (int i = 0; i < 2; i++) {
#pragma unroll
      for (int r = 0; r < 4; r++) {
        C[(size_t)(row0 + i * 16 + r) * 768 + col] = acc[i][j][r] + bv;
      }
    }
  }
}

// ---------- launch ----------
extern "C" void kernel_launch(void* const* d_in, const int* in_sizes, int n_in,
                              void* d_out, int out_size, void* d_ws, size_t ws_size,
                              hipStream_t stream) {
  const float* x     = (const float*)d_in[0];
  const float* Wp    = (const float*)d_in[1];
  const float* bp    = (const float*)d_in[2];
  const float* theta = (const float*)d_in[3];
  const float* Wcf   = (const float*)d_in[4];
  const float* bc    = (const float*)d_in[5];
  float* out = (float*)d_out;

  const size_t EE = (size_t)768 * 768;

  _Float16* WPH = (_Float16*)d_ws;        // [768][768] fp16 W_proj
  _Float16* WCH = WPH + EE;               // [768][768] fp16 W_comb
  _Float16* EZ  = WCH + EE;               // [4096][768] fp16 expz

  // both weight conversions in one launch
  conv_w<<<(int)(2 * EE / 8 / 256), 256, 0, stream>>>(
      (const float4*)Wp, (const float4*)Wcf, (v8h*)WPH, (v8h*)WCH);

  // GEMM1 fused with quantum head: x(fp32) @ Wp^T -> angles -> expz (fp16)
  gemm1_qh<<<768, 256, 0, stream>>>(x, WPH, bp, theta, EZ);

  // GEMM2: out = expz @ Wc^T + bc  (A direct-from-global, B staged)
  gemm2<<<768, 256, 0, stream>>>(EZ, WCH, out, bc);
}

// Round 12
// 98.470 us; speedup vs baseline: 1.1316x; 1.1316x over previous
//
#include <hip/hip_runtime.h>

// ---------- types ----------
typedef _Float16 v8h __attribute__((ext_vector_type(8)));
typedef float    v4f __attribute__((ext_vector_type(4)));

// ---------- helpers ----------
__device__ __forceinline__ void gl_lds16(const void* g, void* l) {
  __builtin_amdgcn_global_load_lds(
      (__attribute__((address_space(1))) void*)(void*)g,
      (__attribute__((address_space(3))) void*)l, 16, 0, 0);
}
__device__ __forceinline__ v8h cvt8(const float4 a, const float4 b) {
  v8h o;
  o[0] = (_Float16)a.x; o[1] = (_Float16)a.y; o[2] = (_Float16)a.z; o[3] = (_Float16)a.w;
  o[4] = (_Float16)b.x; o[5] = (_Float16)b.y; o[6] = (_Float16)b.z; o[7] = (_Float16)b.w;
  return o;
}

// ---------- conversion: both weights fp32 -> fp16 in one launch ----------
__global__ void conv_w(const float4* __restrict__ wp, const float4* __restrict__ wc,
                       v8h* __restrict__ op, v8h* __restrict__ oc) {
  const int n = 73728;  // 768*768/8
  int i = blockIdx.x * blockDim.x + threadIdx.x;
  const float4* src = (i < n) ? wp : wc;
  v8h* dst = (i < n) ? op : oc;
  const int j = (i < n) ? i : i - n;
  dst[j] = cvt8(src[2 * j], src[2 * j + 1]);
}

// ============================================================================
// GEMM structure (round-9 proven): BM=BN=64, BK=128, 6 K-iters, 4 waves each
// 32x32 via 2x2 of 16x16x32_f16 MFMA over 4 K-chunks/iter. LDS 64x128 fp16
// XOR-swizzled (elem (row,cg) at phys cg ^ (row&15); staging permutes the
// GLOBAL address, keeping gl_lds's wave-uniform LDS pattern). Grid 64x12=768
// blocks (3/CU), XCD swizzle: blockIdx%8 -> contiguous 8-M-tile band per XCD.
// gemm1 addition (round 12): X(fp32) register prefetch at depth 1 -- loads for
// iter i+1 issue right AFTER the first barrier of iter i, so their vmcnt(0)
// drain lands at the second barrier, a full compute phase after issue.
// ============================================================================

// ---------- GEMM1 + quantum head, fused ----------
__global__ __launch_bounds__(256) void gemm1_qh(
    const float* __restrict__ X,          // [4096][768] fp32
    const _Float16* __restrict__ B,       // [768][768] fp16 (W_proj)
    const float* __restrict__ bp,         // [768]
    const float* __restrict__ theta,      // [8]
    _Float16* __restrict__ EZ) {          // [4096][768] fp16
  const int t = threadIdx.x;
  const int b = blockIdx.x;
  const int xcd = b & 7, slot = b >> 3;
  const int bm = xcd * 8 + slot / 12;
  const int bn = slot % 12;

  const int wave = t >> 6, lane = t & 63;
  const int quad = lane >> 4, l16 = lane & 15;
  const int wm = (wave >> 1) * 32, wn = (wave & 1) * 32;

  __shared__ __align__(16) unsigned char smem[32768];
  _Float16* As = (_Float16*)smem;            // 64 x 128 (swizzled)
  _Float16* Bs = (_Float16*)(smem + 16384);  // 64 x 128 (swizzled)
  float* Cs = (float*)smem;                  // epilogue reuse: 64 x 68 fp32

  const float4 th0 = *(const float4*)theta;
  const float4 th1 = *(const float4*)(theta + 4);

  const int tr = t >> 4;          // 0..15 (row-in-group)
  const int tc = t & 15;          // col-group
  const int cgl = tc ^ tr;        // swizzled logical col-group for staging

  const float*    Xg = X + (size_t)(bm * 64 + tr) * 768 + cgl * 8;
  const _Float16* Bg = B + (size_t)(bn * 64 + tr) * 768 + cgl * 8;

  v4f acc[2][2];
#pragma unroll
  for (int i = 0; i < 2; i++)
#pragma unroll
    for (int j = 0; j < 2; j++) acc[i][j] = (v4f){0.f, 0.f, 0.f, 0.f};

  // register prefetch: xr holds X data for the iteration about to be staged
  float4 xr[4][2];
#pragma unroll
  for (int c = 0; c < 4; c++) {
    const float* p = Xg + (size_t)c * 16 * 768;
    xr[c][0] = *(const float4*)p;
    xr[c][1] = *(const float4*)(p + 4);
  }

  for (int kt = 0; kt < 768; kt += 128) {
    // stage B (async direct-to-LDS) and A (from prefetched regs)
#pragma unroll
    for (int c = 0; c < 4; c++)
      gl_lds16(Bg + (size_t)c * 16 * 768 + kt, &Bs[c * 2048 + t * 8]);
#pragma unroll
    for (int c = 0; c < 4; c++)
      *(v8h*)&As[c * 2048 + t * 8] = cvt8(xr[c][0], xr[c][1]);
    __syncthreads();
    // issue next iter's X loads NOW: their drain is at the 2nd barrier,
    // a full compute phase after issue
    if (kt + 128 < 768) {
#pragma unroll
      for (int c = 0; c < 4; c++) {
        const float* p = Xg + (size_t)c * 16 * 768 + kt + 128;
        xr[c][0] = *(const float4*)p;
        xr[c][1] = *(const float4*)(p + 4);
      }
    }
#pragma unroll
    for (int q = 0; q < 4; q++) {
      v8h af[2], bf[2];
#pragma unroll
      for (int i = 0; i < 2; i++)
        af[i] = *(const v8h*)&As[(wm + i * 16 + l16) * 128 + (((q * 4 + quad) ^ l16) * 8)];
#pragma unroll
      for (int j = 0; j < 2; j++)
        bf[j] = *(const v8h*)&Bs[(wn + j * 16 + l16) * 128 + (((q * 4 + quad) ^ l16) * 8)];
#pragma unroll
      for (int i = 0; i < 2; i++)
#pragma unroll
        for (int j = 0; j < 2; j++)
          acc[i][j] = __builtin_amdgcn_mfma_f32_16x16x32_f16(af[i], bf[j], acc[i][j], 0, 0, 0);
    }
    __syncthreads();
  }

  // ---- epilogue: acc -> LDS (stride 68), then quantum head per row-head ----
  const int r0 = wm + quad * 4;
  const int c0 = wn + l16;
#pragma unroll
  for (int j = 0; j < 2; j++)
#pragma unroll
    for (int i = 0; i < 2; i++)
#pragma unroll
      for (int r = 0; r < 4; r++)
        Cs[(r0 + i * 16 + r) * 68 + c0 + j * 16] = acc[i][j][r];
  __syncthreads();

#pragma unroll
  for (int s = 0; s < 2; s++) {
    const int idx = t + s * 256;          // 0..511 = 64 rows x 8 heads
    const int row = idx >> 3, h = idx & 7;
    const int gcol = bn * 64 + h * 8;
    const float* cr = &Cs[row * 68 + h * 8];
    const float4 q0 = *(const float4*)cr;
    const float4 q1 = *(const float4*)(cr + 4);
    const float4 b0 = *(const float4*)(bp + gcol);
    const float4 b1 = *(const float4*)(bp + gcol + 4);
    float c[8];
    c[0] = cosf(q0.x + b0.x + th0.x);
    c[1] = cosf(q0.y + b0.y + th0.y);
    c[2] = cosf(q0.z + b0.z + th0.z);
    c[3] = cosf(q0.w + b0.w + th0.w);
    c[4] = cosf(q1.x + b1.x + th1.x);
    c[5] = cosf(q1.y + b1.y + th1.y);
    c[6] = cosf(q1.z + b1.z + th1.z);
    c[7] = cosf(q1.w + b1.w + th1.w);
    float e[8];
    e[0] = c[1] * c[2] * c[3] * c[4] * c[5] * c[6] * c[7];
    float pr = c[0];
#pragma unroll
    for (int w = 1; w < 8; w++) { pr *= c[w]; e[w] = pr; }
    v8h ov;
#pragma unroll
    for (int w = 0; w < 8; w++) ov[w] = (_Float16)e[w];
    *(v8h*)(EZ + (size_t)(bm * 64 + row) * 768 + gcol) = ov;
  }
}

// ---------- GEMM2: out = EZ @ Wc^T + bc, fp16 in, fp32 out (round-9 exact) ----------
__global__ __launch_bounds__(256) void gemm2(
    const _Float16* __restrict__ A,       // [4096][768] fp16 (EZ)
    const _Float16* __restrict__ B,       // [768][768] fp16 (W_comb)
    float* __restrict__ C,                // [4096][768] fp32
    const float* __restrict__ bias) {
  const int t = threadIdx.x;
  const int b = blockIdx.x;
  const int xcd = b & 7, slot = b >> 3;
  const int bm = xcd * 8 + slot / 12;
  const int bn = slot % 12;

  const int wave = t >> 6, lane = t & 63;
  const int quad = lane >> 4, l16 = lane & 15;
  const int wm = (wave >> 1) * 32, wn = (wave & 1) * 32;

  __shared__ __align__(16) _Float16 As[64 * 128];
  __shared__ __align__(16) _Float16 Bs[64 * 128];

  const int tr = t >> 4;
  const int tc = t & 15;
  const int cgl = tc ^ tr;

  const _Float16* Ag = A + (size_t)(bm * 64 + tr) * 768 + cgl * 8;
  const _Float16* Bg = B + (size_t)(bn * 64 + tr) * 768 + cgl * 8;

  v4f acc[2][2];
#pragma unroll
  for (int i = 0; i < 2; i++)
#pragma unroll
    for (int j = 0; j < 2; j++) acc[i][j] = (v4f){0.f, 0.f, 0.f, 0.f};

  for (int kt = 0; kt < 768; kt += 128) {
#pragma unroll
    for (int c = 0; c < 4; c++) {
      gl_lds16(Ag + (size_t)c * 16 * 768 + kt, &As[c * 2048 + t * 8]);
      gl_lds16(Bg + (size_t)c * 16 * 768 + kt, &Bs[c * 2048 + t * 8]);
    }
    __syncthreads();
#pragma unroll
    for (int q = 0; q < 4; q++) {
      v8h af[2], bf[2];
#pragma unroll
      for (int i = 0; i < 2; i++)
        af[i] = *(const v8h*)&As[(wm + i * 16 + l16) * 128 + (((q * 4 + quad) ^ l16) * 8)];
#pragma unroll
      for (int j = 0; j < 2; j++)
        bf[j] = *(const v8h*)&Bs[(wn + j * 16 + l16) * 128 + (((q * 4 + quad) ^ l16) * 8)];
#pragma unroll
      for (int ii = 0; ii < 2; ii++)
#pragma unroll
        for (int j = 0; j < 2; j++)
          acc[ii][j] = __builtin_amdgcn_mfma_f32_16x16x32_f16(af[ii], bf[j], acc[ii][j], 0, 0, 0);
    }
    __syncthreads();
  }

  const int row0 = bm * 64 + wm + quad * 4;
  const int col0 = bn * 64 + wn + l16;
#pragma unroll
  for (int j = 0; j < 2; j++) {
    const int col = col0 + j * 16;
    const float bv = bias[col];
#pragma unroll
    for (int i = 0; i < 2; i++) {
#pragma unroll
      for (int r = 0; r < 4; r++) {
        C[(size_t)(row0 + i * 16 + r) * 768 + col] = acc[i][j][r] + bv;
      }
    }
  }
}

// ---------- launch ----------
extern "C" void kernel_launch(void* const* d_in, const int* in_sizes, int n_in,
                              void* d_out, int out_size, void* d_ws, size_t ws_size,
                              hipStream_t stream) {
  const float* x     = (const float*)d_in[0];
  const float* Wp    = (const float*)d_in[1];
  const float* bp    = (const float*)d_in[2];
  const float* theta = (const float*)d_in[3];
  const float* Wcf   = (const float*)d_in[4];
  const float* bc    = (const float*)d_in[5];
  float* out = (float*)d_out;

  const size_t EE = (size_t)768 * 768;

  _Float16* WPH = (_Float16*)d_ws;        // [768][768] fp16 W_proj
  _Float16* WCH = WPH + EE;               // [768][768] fp16 W_comb
  _Float16* EZ  = WCH + EE;               // [4096][768] fp16 expz

  // both weight conversions in one launch
  conv_w<<<(int)(2 * EE / 8 / 256), 256, 0, stream>>>(
      (const float4*)Wp, (const float4*)Wcf, (v8h*)WPH, (v8h*)WCH);

  // GEMM1 fused with quantum head: x(fp32) @ Wp^T -> angles -> expz (fp16)
  gemm1_qh<<<768, 256, 0, stream>>>(x, WPH, bp, theta, EZ);

  // GEMM2: out = expz @ Wc^T + bc
  gemm2<<<768, 256, 0, stream>>>(EZ, WCH, out, bc);
}